// Round 5
// baseline (191.349 us; speedup 1.0000x reference)
//
#include <hip/hip_runtime.h>
#include <hip/hip_bf16.h>

#define B_ 2
#define H_ 16
#define T_ 2048
#define D_ 64
#define BH (B_*H_)
#define QB 32
#define NW 4

typedef __attribute__((ext_vector_type(8))) short bf16x8;
typedef __attribute__((ext_vector_type(16))) float f32x16;
typedef __attribute__((ext_vector_type(4))) unsigned int u32x4;
typedef unsigned int u32;

__device__ __forceinline__ ushort f2bu(float x){
    __hip_bfloat16 h = __float2bfloat16(x);
    return __builtin_bit_cast(ushort, h);
}
__device__ __forceinline__ u32 cvtpk(float a, float b){
    u32 r; asm("v_cvt_pk_bf16_f32 %0, %1, %2" : "=v"(r) : "v"(a), "v"(b)); return r;
}
// Cross-half (lane ^ 32) reductions via permlane32_swap. The empty asm on b
// forces b into its OWN register: without it the coalescer can fold both
// copies of x into one vreg -> v_permlane32_swap_b32 v, v (self-swap) ->
// reduction returns only the partner value (round-4 NaN bug).
__device__ __forceinline__ float xhalf_max(float x){
    float a = x, b = x;
    asm("" : "+v"(b));
    asm("v_permlane32_swap_b32 %0, %1" : "+v"(a), "+v"(b));
    return fmaxf(a, b);
}
__device__ __forceinline__ float xhalf_sum(float x){
    float a = x, b = x;
    asm("" : "+v"(b));
    asm("v_permlane32_swap_b32 %0, %1" : "+v"(a), "+v"(b));
    return a + b;
}

// transpose f32 [M][N] -> bf16 [N][M] per-bh slab. Optional vm: zero dst row
// (key t = j0+bb) where vmask[b][t]==0  (pad-mask folded into K).
__global__ __launch_bounds__(256) void tr_bf16(const float* __restrict__ src,
        ushort* __restrict__ dst, int M, int N, const float* __restrict__ vm) {
    __shared__ ushort tl[64][65];
    const int bh = blockIdx.x;
    const int i0 = blockIdx.y*64, j0 = blockIdx.z*64;
    const float* s = src + (size_t)bh*M*N;
    ushort*      d = dst + (size_t)bh*M*N;
    const int tid = threadIdx.x;
    const int rr = tid>>4, c4 = (tid&15)*4;
    #pragma unroll
    for (int p=0;p<4;++p){
        int a = p*16+rr;
        float4 x = *reinterpret_cast<const float4*>(&s[(size_t)(i0+a)*N + j0 + c4]);
        tl[c4+0][a]=f2bu(x.x); tl[c4+1][a]=f2bu(x.y);
        tl[c4+2][a]=f2bu(x.z); tl[c4+3][a]=f2bu(x.w);
    }
    __syncthreads();
    #pragma unroll
    for (int p=0;p<4;++p){
        int bb = p*16+rr;
        ushort4 u;
        u.x=tl[bb][c4]; u.y=tl[bb][c4+1]; u.z=tl[bb][c4+2]; u.w=tl[bb][c4+3];
        if (vm && vm[(size_t)(bh>>4)*T_ + j0 + bb] == 0.f) { u.x=0;u.y=0;u.z=0;u.w=0; }
        *reinterpret_cast<ushort4*>(&d[(size_t)(j0+bb)*M + i0 + c4]) = u;
    }
}

// Swapped-operand flash attention, split-KV x4: each of 4 waves in a block
// processes a disjoint chunk of the KV tile range for the SAME 32 q-rows,
// partials merged in LDS (flash-decoding merge). No barriers in main loop.
__global__ __launch_bounds__(NW*64, 4) void attn_fwd(
    const float* __restrict__ q, const float* __restrict__ fp,
    const float* __restrict__ hmask,
    const ushort* __restrict__ KT, const ushort* __restrict__ VT,
    float* __restrict__ out)
{
    const int bid = blockIdx.x;
    const int bh = bid & (BH-1);
    const int qb = (T_/QB - 1) - (bid >> 5);   // heavy-first
    const int i0 = qb*QB;
    const int tid = threadIdx.x;
    const int lane = tid & 63;
    const int wid  = tid >> 6;                 // 0..3 -> KV chunk
    const int col = lane & 31;                 // owned q-row (local)
    const int hi  = lane >> 5;

    const ushort* KTb = KT + (size_t)bh*T_*D_ + (size_t)col*D_ + hi*8;  // [T][D]
    const ushort* VTb = VT + (size_t)bh*T_*D_ + (size_t)col*T_ + hi*8;  // [D][T]

    const float hmv = hmask[(size_t)(bh>>4)*T_ + i0 + col];
    const float sscale = 1.4426950408889634f / fp[0];   // log2(e)/f folded into Q
    const float qs = (hmv != 0.f) ? sscale : 0.f;       // hmask==0 -> row scores all 0
    const float C1E10s = 1e-10f * 1.4426950408889634f;
    const float NINF = -__builtin_inff();

    // Q B-frags (pre-scaled): B[d = dc*16+hi*8+e][col]
    const float* qp = q + (size_t)bh*T_*D_ + (size_t)(i0+col)*D_ + hi*8;
    bf16x8 qf[4];
    #pragma unroll
    for (int dc=0; dc<4; ++dc){
        float4 x0 = *reinterpret_cast<const float4*>(qp + dc*16);
        float4 x1 = *reinterpret_cast<const float4*>(qp + dc*16 + 4);
        u32x4 dw;
        dw[0] = cvtpk(x0.x*qs, x0.y*qs);
        dw[1] = cvtpk(x0.z*qs, x0.w*qs);
        dw[2] = cvtpk(x1.x*qs, x1.y*qs);
        dw[3] = cvtpk(x1.z*qs, x1.w*qs);
        qf[dc] = __builtin_bit_cast(bf16x8, dw);
    }

    float m_run = NINF, l_run = 0.f;
    f32x16 o0, o1;
    #pragma unroll
    for (int r=0;r<16;++r){ o0[r]=0.f; o1[r]=0.f; }

    bf16x8 kf[8];
    auto ldK = [&](int j0v){
        #pragma unroll
        for (int kt=0;kt<2;++kt)
            #pragma unroll
            for (int dc=0;dc<4;++dc)
                kf[kt*4+dc] = *reinterpret_cast<const bf16x8*>(
                    KTb + (size_t)(j0v+kt*32)*D_ + dc*16);
    };

    // split KV tile range [0, nstep) across the 4 waves
    const int nstep = ((i0 + QB - 1) >> 6) + 1;
    const int base = nstep >> 2, rem = nstep & 3;
    const int ts = wid*base + (wid < rem ? wid : rem);
    const int te = ts + base + (wid < rem ? 1 : 0);

    if (ts < te) ldK(ts*64);

    for (int t=ts; t<te; ++t) {
        const int j0 = t*64;

        // S^T = K Q^T  (rows = keys, cols = q)
        f32x16 s0, s1;
        #pragma unroll
        for (int r=0;r<16;++r){ s0[r]=0.f; s1[r]=0.f; }
        #pragma unroll
        for (int dc=0;dc<4;++dc){
            s0 = __builtin_amdgcn_mfma_f32_32x32x16_bf16(kf[dc],   qf[dc], s0, 0,0,0);
            s1 = __builtin_amdgcn_mfma_f32_32x32x16_bf16(kf[4+dc], qf[dc], s1, 0,0,0);
        }

        // V A-frags (issue early; latency hides under softmax)
        bf16x8 vf[8];
        #pragma unroll
        for (int dt=0;dt<2;++dt)
            #pragma unroll
            for (int c2=0;c2<4;++c2)
                vf[dt*4+c2] = *reinterpret_cast<const bf16x8*>(
                    VTb + (size_t)dt*32*T_ + j0 + c2*16);

        // prefetch next K tile
        if (t+1 < te) ldK((t+1)*64);

        // masking: score==0 (K-row or Q-row zeroed) -> 1e-10; causal -> -inf
        if (j0 + 63 <= i0) {
            #pragma unroll
            for (int r=0;r<16;++r){
                float x0v = s0[r]; s0[r] = (x0v==0.f) ? C1E10s : x0v;
                float x1v = s1[r]; s1[r] = (x1v==0.f) ? C1E10s : x1v;
            }
        } else {
            const int th0 = i0 + col - j0 - 4*hi;
            const int th1 = th0 - 32;
            #pragma unroll
            for (int r=0;r<16;++r){
                const int basr = (r&3) + 8*(r>>2);
                float x0v = s0[r]; x0v = (x0v==0.f) ? C1E10s : x0v;
                s0[r] = (basr <= th0) ? x0v : NINF;
                float x1v = s1[r]; x1v = (x1v==0.f) ? C1E10s : x1v;
                s1[r] = (basr <= th1) ? x1v : NINF;
            }
        }

        // online softmax (base-2), one q-row per lane; cross-half via permlane
        float mt = fmaxf(s0[0], s1[0]);
        #pragma unroll
        for (int r=1;r<16;++r) mt = fmaxf(mt, fmaxf(s0[r], s1[r]));
        mt = xhalf_max(mt);
        const float mn = fmaxf(m_run, mt);
        const float fac = __builtin_amdgcn_exp2f(m_run - mn);
        m_run = mn;
        float rs = 0.f;
        #pragma unroll
        for (int r=0;r<16;++r){
            float p0 = __builtin_amdgcn_exp2f(s0[r] - mn);
            float p1 = __builtin_amdgcn_exp2f(s1[r] - mn);
            s0[r]=p0; s1[r]=p1; rs += p0 + p1;
        }
        rs = xhalf_sum(rs);
        l_run = l_run*fac + rs;
        #pragma unroll
        for (int r=0;r<16;++r){ o0[r]*=fac; o1[r]*=fac; }

        // P -> bf16 B-frags: cvt_pk + permlane32_swap (no LDS)
        bf16x8 pb[4];
        #pragma unroll
        for (int c2=0;c2<4;++c2){
            const f32x16& ps = (c2<2) ? s0 : s1;
            const int rb = (c2&1)*8;
            u32 a0 = cvtpk(ps[rb+0], ps[rb+1]);
            u32 a1 = cvtpk(ps[rb+2], ps[rb+3]);
            u32 a2 = cvtpk(ps[rb+4], ps[rb+5]);
            u32 a3 = cvtpk(ps[rb+6], ps[rb+7]);
            asm("v_permlane32_swap_b32 %0, %1" : "+v"(a0), "+v"(a2));
            asm("v_permlane32_swap_b32 %0, %1" : "+v"(a1), "+v"(a3));
            u32x4 dw; dw[0]=a0; dw[1]=a1; dw[2]=a2; dw[3]=a3;
            pb[c2] = __builtin_bit_cast(bf16x8, dw);
        }

        // O^T += V^T P^T
        #pragma unroll
        for (int c2=0;c2<4;++c2){
            o0 = __builtin_amdgcn_mfma_f32_32x32x16_bf16(vf[c2],   pb[c2], o0, 0,0,0);
            o1 = __builtin_amdgcn_mfma_f32_32x32x16_bf16(vf[4+c2], pb[c2], o1, 0,0,0);
        }
    }

    // ---- cross-wave merge (flash-decoding): waves 1-3 publish, wave 0 merges
    __shared__ __align__(16) float Ls[NW-1][64][36];
    if (wid) {
        float* sl = &Ls[wid-1][lane][0];
        #pragma unroll
        for (int q4=0;q4<4;++q4){
            float4 a = {o0[4*q4], o0[4*q4+1], o0[4*q4+2], o0[4*q4+3]};
            *reinterpret_cast<float4*>(sl + 4*q4) = a;
            float4 b = {o1[4*q4], o1[4*q4+1], o1[4*q4+2], o1[4*q4+3]};
            *reinterpret_cast<float4*>(sl + 16 + 4*q4) = b;
        }
        sl[32] = m_run; sl[33] = l_run;
    }
    __syncthreads();
    if (wid) return;

    float M = m_run;
    #pragma unroll
    for (int w=0;w<NW-1;++w) M = fmaxf(M, Ls[w][lane][32]);
    const float ew0 = __builtin_amdgcn_exp2f(m_run - M);
    float L = l_run * ew0;
    #pragma unroll
    for (int r=0;r<16;++r){ o0[r]*=ew0; o1[r]*=ew0; }
    #pragma unroll
    for (int w=0;w<NW-1;++w){
        const float* sl = &Ls[w][lane][0];
        const float mw = sl[32], lw = sl[33];
        const float e2 = __builtin_amdgcn_exp2f(mw - M);
        L += lw * e2;
        #pragma unroll
        for (int q4=0;q4<4;++q4){
            float4 a = *reinterpret_cast<const float4*>(sl + 4*q4);
            o0[4*q4]   += a.x*e2; o0[4*q4+1] += a.y*e2;
            o0[4*q4+2] += a.z*e2; o0[4*q4+3] += a.w*e2;
            float4 b = *reinterpret_cast<const float4*>(sl + 16 + 4*q4);
            o1[4*q4]   += b.x*e2; o1[4*q4+1] += b.y*e2;
            o1[4*q4+2] += b.z*e2; o1[4*q4+3] += b.w*e2;
        }
    }

    // epilogue: O = O^T / L, coalesced float4 stores
    const float rinv = 1.0f / L;
    float* op = out + (size_t)bh*T_*D_ + (size_t)(i0+col)*D_;
    #pragma unroll
    for (int q4=0;q4<4;++q4){
        float4 a = {o0[4*q4]*rinv, o0[4*q4+1]*rinv, o0[4*q4+2]*rinv, o0[4*q4+3]*rinv};
        *reinterpret_cast<float4*>(op + 8*q4 + 4*hi) = a;
        float4 b = {o1[4*q4]*rinv, o1[4*q4+1]*rinv, o1[4*q4+2]*rinv, o1[4*q4+3]*rinv};
        *reinterpret_cast<float4*>(op + 32 + 8*q4 + 4*hi) = b;
    }
}

extern "C" void kernel_launch(void* const* d_in, const int* in_sizes, int n_in,
                              void* d_out, int out_size, void* d_ws, size_t ws_size,
                              hipStream_t stream) {
    const float* q  = (const float*)d_in[0];
    const float* k  = (const float*)d_in[1];
    const float* v  = (const float*)d_in[2];
    const float* f  = (const float*)d_in[3];
    const float* vm = (const float*)d_in[4];
    const float* hm = (const float*)d_in[5];
    float* out = (float*)d_out;

    const size_t slab = (size_t)BH * T_ * D_;
    ushort* KT = (ushort*)d_ws;
    ushort* VT = KT + slab;

    // k: f32 [D][T] -> KT bf16 [T][D], vmask'd rows zeroed
    hipLaunchKernelGGL(tr_bf16, dim3(BH, 1, T_/64), dim3(256), 0, stream,
                       k, KT, D_, T_, vm);
    // v: f32 [T][D] -> VT bf16 [D][T]
    hipLaunchKernelGGL(tr_bf16, dim3(BH, T_/64, 1), dim3(256), 0, stream,
                       v, VT, T_, D_, (const float*)nullptr);

    dim3 grid(BH * (T_/QB));   // 2048 blocks x 4 waves (split-KV)
    dim3 block(NW*64);
    hipLaunchKernelGGL(attn_fwd, grid, block, 0, stream, q, f, hm, KT, VT, out);
}

// Round 6
// 90.393 us; speedup vs baseline: 2.1169x; 2.1169x over previous
//
#include <hip/hip_runtime.h>
#include <hip/hip_bf16.h>

#define B_ 2
#define H_ 16
#define T_ 2048
#define D_ 64
#define BH (B_*H_)
#define QB 32
#define NW 4

typedef __attribute__((ext_vector_type(8))) short bf16x8;
typedef __attribute__((ext_vector_type(16))) float f32x16;
typedef __attribute__((ext_vector_type(4))) unsigned int u32x4;
typedef unsigned int u32;

__device__ __forceinline__ ushort f2bu(float x){
    __hip_bfloat16 h = __float2bfloat16(x);
    return __builtin_bit_cast(ushort, h);
}
__device__ __forceinline__ u32 cvtpk(float a, float b){
    u32 r; asm("v_cvt_pk_bf16_f32 %0, %1, %2" : "=v"(r) : "v"(a), "v"(b)); return r;
}
// Cross-half (lane ^ 32) reductions via permlane32_swap. The empty asm on b
// forces b into its OWN register (round-4 lesson: without it the coalescer
// folds both copies into one vreg -> self-swap -> wrong reduction -> NaN).
__device__ __forceinline__ float xhalf_max(float x){
    float a = x, b = x;
    asm("" : "+v"(b));
    asm("v_permlane32_swap_b32 %0, %1" : "+v"(a), "+v"(b));
    return fmaxf(a, b);
}
__device__ __forceinline__ float xhalf_sum(float x){
    float a = x, b = x;
    asm("" : "+v"(b));
    asm("v_permlane32_swap_b32 %0, %1" : "+v"(a), "+v"(b));
    return a + b;
}

// transpose f32 [M][N] -> bf16 [N][M] per-bh slab. Optional vm: zero dst row
// (key t = j0+bb) where vmask[b][t]==0  (pad-mask folded into K).
__global__ __launch_bounds__(256) void tr_bf16(const float* __restrict__ src,
        ushort* __restrict__ dst, int M, int N, const float* __restrict__ vm) {
    __shared__ ushort tl[64][65];
    const int bh = blockIdx.x;
    const int i0 = blockIdx.y*64, j0 = blockIdx.z*64;
    const float* s = src + (size_t)bh*M*N;
    ushort*      d = dst + (size_t)bh*M*N;
    const int tid = threadIdx.x;
    const int rr = tid>>4, c4 = (tid&15)*4;
    #pragma unroll
    for (int p=0;p<4;++p){
        int a = p*16+rr;
        float4 x = *reinterpret_cast<const float4*>(&s[(size_t)(i0+a)*N + j0 + c4]);
        tl[c4+0][a]=f2bu(x.x); tl[c4+1][a]=f2bu(x.y);
        tl[c4+2][a]=f2bu(x.z); tl[c4+3][a]=f2bu(x.w);
    }
    __syncthreads();
    #pragma unroll
    for (int p=0;p<4;++p){
        int bb = p*16+rr;
        ushort4 u;
        u.x=tl[bb][c4]; u.y=tl[bb][c4+1]; u.z=tl[bb][c4+2]; u.w=tl[bb][c4+3];
        if (vm && vm[(size_t)(bh>>4)*T_ + j0 + bb] == 0.f) { u.x=0;u.y=0;u.z=0;u.w=0; }
        *reinterpret_cast<ushort4*>(&d[(size_t)(j0+bb)*M + i0 + c4]) = u;
    }
}

// Swapped-operand flash attention, split-KV x4. launch_bounds(256,3):
// VGPR cap ~170 -> NO spill (round-5 lesson: (256,4) forced 64 VGPR and
// 324 MB of scratch spill traffic). No K-prefetch: TLP (3 waves/SIMD)
// hides latency instead of ILP, keeping peak live regs ~135.
__global__ __launch_bounds__(NW*64, 3) void attn_fwd(
    const float* __restrict__ q, const float* __restrict__ fp,
    const float* __restrict__ hmask,
    const ushort* __restrict__ KT, const ushort* __restrict__ VT,
    float* __restrict__ out)
{
    const int bid = blockIdx.x;
    const int bh = bid & (BH-1);
    const int qb = (T_/QB - 1) - (bid >> 5);   // heavy-first
    const int i0 = qb*QB;
    const int tid = threadIdx.x;
    const int lane = tid & 63;
    const int wid  = tid >> 6;                 // 0..3 -> KV chunk
    const int col = lane & 31;                 // owned q-row (local)
    const int hi  = lane >> 5;

    const ushort* KTb = KT + (size_t)bh*T_*D_ + (size_t)col*D_ + hi*8;  // [T][D]
    const ushort* VTb = VT + (size_t)bh*T_*D_ + (size_t)col*T_ + hi*8;  // [D][T]

    const float hmv = hmask[(size_t)(bh>>4)*T_ + i0 + col];
    const float sscale = 1.4426950408889634f / fp[0];   // log2(e)/f folded into Q
    const float qs = (hmv != 0.f) ? sscale : 0.f;       // hmask==0 -> row scores all 0
    const float C1E10s = 1e-10f * 1.4426950408889634f;
    const float NINF = -__builtin_inff();

    // Q B-frags (pre-scaled): B[d = dc*16+hi*8+e][col]
    const float* qp = q + (size_t)bh*T_*D_ + (size_t)(i0+col)*D_ + hi*8;
    bf16x8 qf[4];
    #pragma unroll
    for (int dc=0; dc<4; ++dc){
        float4 x0 = *reinterpret_cast<const float4*>(qp + dc*16);
        float4 x1 = *reinterpret_cast<const float4*>(qp + dc*16 + 4);
        u32x4 dw;
        dw[0] = cvtpk(x0.x*qs, x0.y*qs);
        dw[1] = cvtpk(x0.z*qs, x0.w*qs);
        dw[2] = cvtpk(x1.x*qs, x1.y*qs);
        dw[3] = cvtpk(x1.z*qs, x1.w*qs);
        qf[dc] = __builtin_bit_cast(bf16x8, dw);
    }

    float m_run = NINF, l_run = 0.f;
    f32x16 o0, o1;
    #pragma unroll
    for (int r=0;r<16;++r){ o0[r]=0.f; o1[r]=0.f; }

    // split KV tile range [0, nstep) across the 4 waves
    const int nstep = ((i0 + QB - 1) >> 6) + 1;
    const int base = nstep >> 2, rem = nstep & 3;
    const int ts = wid*base + (wid < rem ? wid : rem);
    const int te = ts + base + (wid < rem ? 1 : 0);

    for (int t=ts; t<te; ++t) {
        const int j0 = t*64;

        // K tile for this step (no prefetch: keeps peak regs under the cap)
        bf16x8 kf[8];
        #pragma unroll
        for (int kt=0;kt<2;++kt)
            #pragma unroll
            for (int dc=0;dc<4;++dc)
                kf[kt*4+dc] = *reinterpret_cast<const bf16x8*>(
                    KTb + (size_t)(j0+kt*32)*D_ + dc*16);

        // S^T = K Q^T  (rows = keys, cols = q)
        f32x16 s0, s1;
        #pragma unroll
        for (int r=0;r<16;++r){ s0[r]=0.f; s1[r]=0.f; }
        #pragma unroll
        for (int dc=0;dc<4;++dc){
            s0 = __builtin_amdgcn_mfma_f32_32x32x16_bf16(kf[dc],   qf[dc], s0, 0,0,0);
            s1 = __builtin_amdgcn_mfma_f32_32x32x16_bf16(kf[4+dc], qf[dc], s1, 0,0,0);
        }

        // V A-frags (issue early; latency hides under softmax)
        bf16x8 vf[8];
        #pragma unroll
        for (int dt=0;dt<2;++dt)
            #pragma unroll
            for (int c2=0;c2<4;++c2)
                vf[dt*4+c2] = *reinterpret_cast<const bf16x8*>(
                    VTb + (size_t)dt*32*T_ + j0 + c2*16);

        // masking: score==0 (K-row or Q-row zeroed) -> 1e-10; causal -> -inf
        if (j0 + 63 <= i0) {
            #pragma unroll
            for (int r=0;r<16;++r){
                float x0v = s0[r]; s0[r] = (x0v==0.f) ? C1E10s : x0v;
                float x1v = s1[r]; s1[r] = (x1v==0.f) ? C1E10s : x1v;
            }
        } else {
            const int th0 = i0 + col - j0 - 4*hi;
            const int th1 = th0 - 32;
            #pragma unroll
            for (int r=0;r<16;++r){
                const int basr = (r&3) + 8*(r>>2);
                float x0v = s0[r]; x0v = (x0v==0.f) ? C1E10s : x0v;
                s0[r] = (basr <= th0) ? x0v : NINF;
                float x1v = s1[r]; x1v = (x1v==0.f) ? C1E10s : x1v;
                s1[r] = (basr <= th1) ? x1v : NINF;
            }
        }

        // online softmax (base-2), one q-row per lane; cross-half via permlane
        float mt = fmaxf(s0[0], s1[0]);
        #pragma unroll
        for (int r=1;r<16;++r) mt = fmaxf(mt, fmaxf(s0[r], s1[r]));
        mt = xhalf_max(mt);
        const float mn = fmaxf(m_run, mt);
        const float fac = __builtin_amdgcn_exp2f(m_run - mn);
        m_run = mn;
        float rs = 0.f;
        #pragma unroll
        for (int r=0;r<16;++r){
            float p0 = __builtin_amdgcn_exp2f(s0[r] - mn);
            float p1 = __builtin_amdgcn_exp2f(s1[r] - mn);
            s0[r]=p0; s1[r]=p1; rs += p0 + p1;
        }
        rs = xhalf_sum(rs);
        l_run = l_run*fac + rs;
        #pragma unroll
        for (int r=0;r<16;++r){ o0[r]*=fac; o1[r]*=fac; }

        // P -> bf16 B-frags: cvt_pk + permlane32_swap (no LDS)
        bf16x8 pb[4];
        #pragma unroll
        for (int c2=0;c2<4;++c2){
            const f32x16& ps = (c2<2) ? s0 : s1;
            const int rb = (c2&1)*8;
            u32 a0 = cvtpk(ps[rb+0], ps[rb+1]);
            u32 a1 = cvtpk(ps[rb+2], ps[rb+3]);
            u32 a2 = cvtpk(ps[rb+4], ps[rb+5]);
            u32 a3 = cvtpk(ps[rb+6], ps[rb+7]);
            asm("v_permlane32_swap_b32 %0, %1" : "+v"(a0), "+v"(a2));
            asm("v_permlane32_swap_b32 %0, %1" : "+v"(a1), "+v"(a3));
            u32x4 dw; dw[0]=a0; dw[1]=a1; dw[2]=a2; dw[3]=a3;
            pb[c2] = __builtin_bit_cast(bf16x8, dw);
        }

        // O^T += V^T P^T
        #pragma unroll
        for (int c2=0;c2<4;++c2){
            o0 = __builtin_amdgcn_mfma_f32_32x32x16_bf16(vf[c2],   pb[c2], o0, 0,0,0);
            o1 = __builtin_amdgcn_mfma_f32_32x32x16_bf16(vf[4+c2], pb[c2], o1, 0,0,0);
        }
    }

    // ---- cross-wave merge (flash-decoding): waves 1-3 publish, wave 0 merges
    __shared__ __align__(16) float Ls[NW-1][64][36];
    if (wid) {
        float* sl = &Ls[wid-1][lane][0];
        #pragma unroll
        for (int q4=0;q4<4;++q4){
            float4 a = {o0[4*q4], o0[4*q4+1], o0[4*q4+2], o0[4*q4+3]};
            *reinterpret_cast<float4*>(sl + 4*q4) = a;
            float4 b = {o1[4*q4], o1[4*q4+1], o1[4*q4+2], o1[4*q4+3]};
            *reinterpret_cast<float4*>(sl + 16 + 4*q4) = b;
        }
        sl[32] = m_run; sl[33] = l_run;
    }
    __syncthreads();
    if (wid) return;

    float M = m_run;
    #pragma unroll
    for (int w=0;w<NW-1;++w) M = fmaxf(M, Ls[w][lane][32]);
    const float ew0 = __builtin_amdgcn_exp2f(m_run - M);
    float L = l_run * ew0;
    #pragma unroll
    for (int r=0;r<16;++r){ o0[r]*=ew0; o1[r]*=ew0; }
    #pragma unroll
    for (int w=0;w<NW-1;++w){
        const float* sl = &Ls[w][lane][0];
        const float mw = sl[32], lw = sl[33];
        const float e2 = __builtin_amdgcn_exp2f(mw - M);
        L += lw * e2;
        #pragma unroll
        for (int q4=0;q4<4;++q4){
            float4 a = *reinterpret_cast<const float4*>(sl + 4*q4);
            o0[4*q4]   += a.x*e2; o0[4*q4+1] += a.y*e2;
            o0[4*q4+2] += a.z*e2; o0[4*q4+3] += a.w*e2;
            float4 b = *reinterpret_cast<const float4*>(sl + 16 + 4*q4);
            o1[4*q4]   += b.x*e2; o1[4*q4+1] += b.y*e2;
            o1[4*q4+2] += b.z*e2; o1[4*q4+3] += b.w*e2;
        }
    }

    // epilogue: O = O^T / L, coalesced float4 stores
    const float rinv = 1.0f / L;
    float* op = out + (size_t)bh*T_*D_ + (size_t)(i0+col)*D_;
    #pragma unroll
    for (int q4=0;q4<4;++q4){
        float4 a = {o0[4*q4]*rinv, o0[4*q4+1]*rinv, o0[4*q4+2]*rinv, o0[4*q4+3]*rinv};
        *reinterpret_cast<float4*>(op + 8*q4 + 4*hi) = a;
        float4 b = {o1[4*q4]*rinv, o1[4*q4+1]*rinv, o1[4*q4+2]*rinv, o1[4*q4+3]*rinv};
        *reinterpret_cast<float4*>(op + 32 + 8*q4 + 4*hi) = b;
    }
}

extern "C" void kernel_launch(void* const* d_in, const int* in_sizes, int n_in,
                              void* d_out, int out_size, void* d_ws, size_t ws_size,
                              hipStream_t stream) {
    const float* q  = (const float*)d_in[0];
    const float* k  = (const float*)d_in[1];
    const float* v  = (const float*)d_in[2];
    const float* f  = (const float*)d_in[3];
    const float* vm = (const float*)d_in[4];
    const float* hm = (const float*)d_in[5];
    float* out = (float*)d_out;

    const size_t slab = (size_t)BH * T_ * D_;
    ushort* KT = (ushort*)d_ws;
    ushort* VT = KT + slab;

    // k: f32 [D][T] -> KT bf16 [T][D], vmask'd rows zeroed
    hipLaunchKernelGGL(tr_bf16, dim3(BH, 1, T_/64), dim3(256), 0, stream,
                       k, KT, D_, T_, vm);
    // v: f32 [T][D] -> VT bf16 [D][T]
    hipLaunchKernelGGL(tr_bf16, dim3(BH, T_/64, 1), dim3(256), 0, stream,
                       v, VT, T_, D_, (const float*)nullptr);

    dim3 grid(BH * (T_/QB));   // 2048 blocks x 4 waves (split-KV)
    dim3 block(NW*64);
    hipLaunchKernelGGL(attn_fwd, grid, block, 0, stream, q, f, hm, KT, VT, out);
}

// Round 10
// 68.623 us; speedup vs baseline: 2.7884x; 1.3172x over previous
//
#include <hip/hip_runtime.h>
#include <hip/hip_bf16.h>

#define B_ 2
#define H_ 16
#define T_ 2048
#define D_ 64
#define BH (B_*H_)
#define QBW 32            // q rows per wave
#define NW 4              // waves per block
#define QBLK (QBW*NW)     // 128 q rows per block

typedef __attribute__((ext_vector_type(8))) short bf16x8;
typedef __attribute__((ext_vector_type(16))) float f32x16;
typedef __attribute__((ext_vector_type(4))) unsigned int u32x4;
typedef unsigned int u32;

typedef __attribute__((address_space(3))) void lds_void;
typedef __attribute__((address_space(1))) const void gbl_void;

__device__ __forceinline__ ushort f2bu(float x){
    __hip_bfloat16 h = __float2bfloat16(x);
    return __builtin_bit_cast(ushort, h);
}
__device__ __forceinline__ u32 cvtpk(float a, float b){
    u32 r; asm("v_cvt_pk_bf16_f32 %0, %1, %2" : "=v"(r) : "v"(a), "v"(b)); return r;
}
// Cross-half (lane ^ 32) reductions via permlane32_swap. Empty asm on b keeps
// it in its OWN register (round-4 lesson: coalescer self-swap bug -> NaN).
__device__ __forceinline__ float xhalf_max(float x){
    float a = x, b = x;
    asm("" : "+v"(b));
    asm("v_permlane32_swap_b32 %0, %1" : "+v"(a), "+v"(b));
    return fmaxf(a, b);
}
__device__ __forceinline__ float xhalf_sum(float x){
    float a = x, b = x;
    asm("" : "+v"(b));
    asm("v_permlane32_swap_b32 %0, %1" : "+v"(a), "+v"(b));
    return a + b;
}

// transpose f32 [M][N] -> bf16 [N][M] per-bh slab (PROVEN: rounds 2-6).
// Optional vm: zero dst row (key t = j0+bb) where vmask[b][t]==0.
__global__ __launch_bounds__(256) void tr_bf16(const float* __restrict__ src,
        ushort* __restrict__ dst, int M, int N, const float* __restrict__ vm) {
    __shared__ ushort tl[64][65];
    const int bh = blockIdx.x;
    const int i0 = blockIdx.y*64, j0 = blockIdx.z*64;
    const float* s = src + (size_t)bh*M*N;
    ushort*      d = dst + (size_t)bh*M*N;
    const int tid = threadIdx.x;
    const int rr = tid>>4, c4 = (tid&15)*4;
    #pragma unroll
    for (int p=0;p<4;++p){
        int a = p*16+rr;
        float4 x = *reinterpret_cast<const float4*>(&s[(size_t)(i0+a)*N + j0 + c4]);
        tl[c4+0][a]=f2bu(x.x); tl[c4+1][a]=f2bu(x.y);
        tl[c4+2][a]=f2bu(x.z); tl[c4+3][a]=f2bu(x.w);
    }
    __syncthreads();
    #pragma unroll
    for (int p=0;p<4;++p){
        int bb = p*16+rr;
        ushort4 u;
        u.x=tl[bb][c4]; u.y=tl[bb][c4+1]; u.z=tl[bb][c4+2]; u.w=tl[bb][c4+3];
        if (vm && vm[(size_t)(bh>>4)*T_ + j0 + bb] == 0.f) { u.x=0;u.y=0;u.z=0;u.w=0; }
        *reinterpret_cast<ushort4*>(&d[(size_t)(j0+bb)*M + i0 + c4]) = u;
    }
}

// Cooperative-tile flash attention: 4 waves x 32 q-rows share LDS-staged
// K/V tiles (64 keys). Staging: global_load_lds w16, linear LDS dest,
// pre-swizzled global source (XOR involution on bits 4-6 keyed by row&7).
// Triple-buffered, counted vmcnt(4), one barrier per tile.
__global__ __launch_bounds__(NW*64, 3) void attn_fwd(
    const float* __restrict__ q, const float* __restrict__ fp,
    const float* __restrict__ hmask,
    const ushort* __restrict__ KT,   // bf16 [T][D] per bh (vmask'd rows zeroed)
    const ushort* __restrict__ VT,   // bf16 [D][T] per bh
    float* __restrict__ out)
{
    __shared__ __align__(16) ushort sK[3][4096];   // 3 x 8KB
    __shared__ __align__(16) ushort sV[3][4096];   // 3 x 8KB

    const int bid = blockIdx.x;
    const int bh = bid & (BH-1);
    const int qb = (T_/QBLK - 1) - (bid >> 5);     // heavy-first (15..0)
    const int tid = threadIdx.x;
    const int lane = tid & 63;
    const int wid  = tid >> 6;
    const int col = lane & 31;
    const int hi  = lane >> 5;
    const int i0w = qb*QBLK + wid*QBW;             // this wave's 32 q-rows

    const ushort* KTb = KT + (size_t)bh*T_*D_;
    const ushort* VTb = VT + (size_t)bh*T_*D_;

    const float hmv = hmask[(size_t)(bh>>4)*T_ + i0w + col];
    const float sscale = 1.4426950408889634f / fp[0];
    const float qs = (hmv != 0.f) ? sscale : 0.f;
    const float C1E10s = 1e-10f * 1.4426950408889634f;
    const float NINF = -__builtin_inff();

    // Q B-frags (pre-scaled): B[d = dc*16+hi*8+e][col]   (round-3..6 proven)
    const float* qp = q + (size_t)bh*T_*D_ + (size_t)(i0w+col)*D_ + hi*8;
    bf16x8 qf[4];
    #pragma unroll
    for (int dc=0; dc<4; ++dc){
        float4 x0 = *reinterpret_cast<const float4*>(qp + dc*16);
        float4 x1 = *reinterpret_cast<const float4*>(qp + dc*16 + 4);
        u32x4 dw;
        dw[0] = cvtpk(x0.x*qs, x0.y*qs);
        dw[1] = cvtpk(x0.z*qs, x0.w*qs);
        dw[2] = cvtpk(x1.x*qs, x1.y*qs);
        dw[3] = cvtpk(x1.z*qs, x1.w*qs);
        qf[dc] = __builtin_bit_cast(bf16x8, dw);
    }

    float m_run = NINF, l_run = 0.f;
    f32x16 o0, o1;
    #pragma unroll
    for (int r=0;r<16;++r){ o0[r]=0.f; o1[r]=0.f; }

    const unsigned uoff = (unsigned)(wid*1024 + lane*16);  // staging byte cursor
    const unsigned swz = ((unsigned)(col&7)) << 4;         // frag-read swizzle

    // stage tile t into buffer b: K rows are contiguous (KT row = 64 elem =
    // tile row); V rows strided T. LDS dest linear (wave-uniform base);
    // global source pre-swizzled by the same involution used on reads.
    auto stage = [&](int b, int t){
        const char* kbase = (const char*)KTb + (size_t)t*8192;   // j0*128 B
        #pragma unroll
        for (int i=0;i<2;++i){
            const unsigned u = i*4096u + uoff;
            const unsigned su = u ^ (((u>>7)&7u)<<4);
            __builtin_amdgcn_global_load_lds(
                (gbl_void*)(kbase + su),
                (lds_void*)((char*)&sK[b][0] + i*4096 + wid*1024), 16, 0, 0);
        }
        #pragma unroll
        for (int i=0;i<2;++i){
            const unsigned u = i*4096u + uoff;
            const unsigned dR = u>>7;                 // tile row = d
            const unsigned inr = (u&127u) ^ ((dR&7u)<<4);
            const char* src = (const char*)VTb + (size_t)dR*(T_*2) + (size_t)t*128 + inr;
            __builtin_amdgcn_global_load_lds(
                (gbl_void*)src,
                (lds_void*)((char*)&sV[b][0] + i*4096 + wid*1024), 16, 0, 0);
        }
    };

    const int ntiles = 2*qb + 2;    // covers keys 0 .. qb*128+127
    int buf = 0;
    stage(0, 0);

    for (int t=0; t<ntiles; ++t){
        const int j0 = t*64;
        const int nb = (buf==2) ? 0 : buf+1;
        if (t+1 < ntiles){
            stage(nb, t+1);
            asm volatile("s_waitcnt vmcnt(4)" ::: "memory");  // tile-t landed
        } else {
            asm volatile("s_waitcnt vmcnt(0)" ::: "memory");
        }
        __builtin_amdgcn_s_barrier();

        if (j0 <= i0w + QBW - 1){   // wave-uniform causal relevance
            // K frags from LDS: r = (kt*32+col)*128 + dc*32 + hi*16, ^swz
            const char* sKb = (const char*)&sK[buf][0];
            bf16x8 kf[8];
            #pragma unroll
            for (int kt=0;kt<2;++kt)
                #pragma unroll
                for (int dc=0;dc<4;++dc)
                    kf[kt*4+dc] = *reinterpret_cast<const bf16x8*>(
                        sKb + (((unsigned)(kt*4096 + dc*32 + col*128 + hi*16)) ^ swz));

            f32x16 s0, s1;
            #pragma unroll
            for (int r=0;r<16;++r){ s0[r]=0.f; s1[r]=0.f; }
            #pragma unroll
            for (int dc=0;dc<4;++dc){
                s0 = __builtin_amdgcn_mfma_f32_32x32x16_bf16(kf[dc],   qf[dc], s0, 0,0,0);
                s1 = __builtin_amdgcn_mfma_f32_32x32x16_bf16(kf[4+dc], qf[dc], s1, 0,0,0);
            }

            // V frags: r = (dt*32+col)*128 + c2*32 + hi*16, ^swz
            const char* sVb = (const char*)&sV[buf][0];
            bf16x8 vf[8];
            #pragma unroll
            for (int f=0;f<8;++f)
                vf[f] = *reinterpret_cast<const bf16x8*>(
                    sVb + (((unsigned)((f>>2)*4096 + (f&3)*32 + col*128 + hi*16)) ^ swz));

            // masking: score==0 -> 1e-10 ; causal -> -inf   (rounds 3-6 proven)
            if (j0 + 63 <= i0w) {
                #pragma unroll
                for (int r=0;r<16;++r){
                    float x0v = s0[r]; s0[r] = (x0v==0.f) ? C1E10s : x0v;
                    float x1v = s1[r]; s1[r] = (x1v==0.f) ? C1E10s : x1v;
                }
            } else {
                const int th0 = i0w + col - j0 - 4*hi;
                const int th1 = th0 - 32;
                #pragma unroll
                for (int r=0;r<16;++r){
                    const int basr = (r&3) + 8*(r>>2);
                    float x0v = s0[r]; x0v = (x0v==0.f) ? C1E10s : x0v;
                    s0[r] = (basr <= th0) ? x0v : NINF;
                    float x1v = s1[r]; x1v = (x1v==0.f) ? C1E10s : x1v;
                    s1[r] = (basr <= th1) ? x1v : NINF;
                }
            }

            // online softmax (base-2), serial-chain reduce (rounds 3-6 proven)
            float mt = fmaxf(s0[0], s1[0]);
            #pragma unroll
            for (int r=1;r<16;++r) mt = fmaxf(mt, fmaxf(s0[r], s1[r]));
            mt = xhalf_max(mt);
            const float mn = fmaxf(m_run, mt);
            const float fac = __builtin_amdgcn_exp2f(m_run - mn);
            m_run = mn;
            float rs = 0.f;
            #pragma unroll
            for (int r=0;r<16;++r){
                float p0 = __builtin_amdgcn_exp2f(s0[r] - mn);
                float p1 = __builtin_amdgcn_exp2f(s1[r] - mn);
                s0[r]=p0; s1[r]=p1; rs += p0 + p1;
            }
            rs = xhalf_sum(rs);
            l_run = l_run*fac + rs;
            #pragma unroll
            for (int r=0;r<16;++r){ o0[r]*=fac; o1[r]*=fac; }

            // P -> bf16 B-frags (rounds 3-6 proven)
            bf16x8 pb[4];
            #pragma unroll
            for (int c2=0;c2<4;++c2){
                const f32x16& ps = (c2<2) ? s0 : s1;
                const int rb = (c2&1)*8;
                u32 a0 = cvtpk(ps[rb+0], ps[rb+1]);
                u32 a1 = cvtpk(ps[rb+2], ps[rb+3]);
                u32 a2 = cvtpk(ps[rb+4], ps[rb+5]);
                u32 a3 = cvtpk(ps[rb+6], ps[rb+7]);
                asm("v_permlane32_swap_b32 %0, %1" : "+v"(a0), "+v"(a2));
                asm("v_permlane32_swap_b32 %0, %1" : "+v"(a1), "+v"(a3));
                u32x4 dw; dw[0]=a0; dw[1]=a1; dw[2]=a2; dw[3]=a3;
                pb[c2] = __builtin_bit_cast(bf16x8, dw);
            }

            // O^T += V^T P^T
            #pragma unroll
            for (int c2=0;c2<4;++c2){
                o0 = __builtin_amdgcn_mfma_f32_32x32x16_bf16(vf[c2],   pb[c2], o0, 0,0,0);
                o1 = __builtin_amdgcn_mfma_f32_32x32x16_bf16(vf[4+c2], pb[c2], o1, 0,0,0);
            }
        }
        buf = nb;
    }

    // epilogue: O = O^T / l  (no cross-wave merge; each wave owns its rows)
    const float rinv = 1.0f / l_run;
    float* op = out + (size_t)bh*T_*D_ + (size_t)(i0w+col)*D_;
    #pragma unroll
    for (int q4=0;q4<4;++q4){
        float4 a = {o0[4*q4]*rinv, o0[4*q4+1]*rinv, o0[4*q4+2]*rinv, o0[4*q4+3]*rinv};
        *reinterpret_cast<float4*>(op + 8*q4 + 4*hi) = a;
        float4 b = {o1[4*q4]*rinv, o1[4*q4+1]*rinv, o1[4*q4+2]*rinv, o1[4*q4+3]*rinv};
        *reinterpret_cast<float4*>(op + 32 + 8*q4 + 4*hi) = b;
    }
}

extern "C" void kernel_launch(void* const* d_in, const int* in_sizes, int n_in,
                              void* d_out, int out_size, void* d_ws, size_t ws_size,
                              hipStream_t stream) {
    const float* q  = (const float*)d_in[0];
    const float* k  = (const float*)d_in[1];
    const float* v  = (const float*)d_in[2];
    const float* f  = (const float*)d_in[3];
    const float* vm = (const float*)d_in[4];
    const float* hm = (const float*)d_in[5];
    float* out = (float*)d_out;

    const size_t slab = (size_t)BH * T_ * D_;
    ushort* KT = (ushort*)d_ws;
    ushort* VT = KT + slab;

    // k: f32 [D][T] -> KT bf16 [T][D], vmask'd rows zeroed  (proven prep)
    hipLaunchKernelGGL(tr_bf16, dim3(BH, 1, T_/64), dim3(256), 0, stream,
                       k, KT, D_, T_, vm);
    // v: f32 [T][D] -> VT bf16 [D][T]
    hipLaunchKernelGGL(tr_bf16, dim3(BH, T_/64, 1), dim3(256), 0, stream,
                       v, VT, T_, D_, (const float*)nullptr);

    dim3 grid(BH * (T_/QBLK));   // 512 blocks x 4 waves, cooperative tiles
    dim3 block(NW*64);
    hipLaunchKernelGGL(attn_fwd, grid, block, 0, stream, q, f, hm, KT, VT, out);
}

// Round 11
// 67.997 us; speedup vs baseline: 2.8141x; 1.0092x over previous
//
#include <hip/hip_runtime.h>
#include <hip/hip_bf16.h>

#define B_ 2
#define H_ 16
#define T_ 2048
#define D_ 64
#define BH (B_*H_)

typedef __attribute__((ext_vector_type(8))) short bf16x8;
typedef __attribute__((ext_vector_type(16))) float f32x16;
typedef __attribute__((ext_vector_type(4))) unsigned int u32x4;
typedef unsigned int u32;

typedef __attribute__((address_space(3))) void lds_void;
typedef __attribute__((address_space(1))) const void gbl_void;

__device__ __forceinline__ ushort f2bu(float x){
    __hip_bfloat16 h = __float2bfloat16(x);
    return __builtin_bit_cast(ushort, h);
}
__device__ __forceinline__ u32 cvtpk(float a, float b){
    u32 r; asm("v_cvt_pk_bf16_f32 %0, %1, %2" : "=v"(r) : "v"(a), "v"(b)); return r;
}
// Cross-half (lane ^ 32) reductions via permlane32_swap. Empty asm on b keeps
// it in its OWN register (round-4 lesson: coalescer self-swap bug -> NaN).
__device__ __forceinline__ float xhalf_max(float x){
    float a = x, b = x;
    asm("" : "+v"(b));
    asm("v_permlane32_swap_b32 %0, %1" : "+v"(a), "+v"(b));
    return fmaxf(a, b);
}
__device__ __forceinline__ float xhalf_sum(float x){
    float a = x, b = x;
    asm("" : "+v"(b));
    asm("v_permlane32_swap_b32 %0, %1" : "+v"(a), "+v"(b));
    return a + b;
}

// transpose f32 [M][N] -> bf16 [N][M] per-bh slab (PROVEN: rounds 2-10).
// Optional vm: zero dst row (key t = j0+bb) where vmask[b][t]==0.
__global__ __launch_bounds__(256) void tr_bf16(const float* __restrict__ src,
        ushort* __restrict__ dst, int M, int N, const float* __restrict__ vm) {
    __shared__ ushort tl[64][65];
    const int bh = blockIdx.x;
    const int i0 = blockIdx.y*64, j0 = blockIdx.z*64;
    const float* s = src + (size_t)bh*M*N;
    ushort*      d = dst + (size_t)bh*M*N;
    const int tid = threadIdx.x;
    const int rr = tid>>4, c4 = (tid&15)*4;
    #pragma unroll
    for (int p=0;p<4;++p){
        int a = p*16+rr;
        float4 x = *reinterpret_cast<const float4*>(&s[(size_t)(i0+a)*N + j0 + c4]);
        tl[c4+0][a]=f2bu(x.x); tl[c4+1][a]=f2bu(x.y);
        tl[c4+2][a]=f2bu(x.z); tl[c4+3][a]=f2bu(x.w);
    }
    __syncthreads();
    #pragma unroll
    for (int p=0;p<4;++p){
        int bb = p*16+rr;
        ushort4 u;
        u.x=tl[bb][c4]; u.y=tl[bb][c4+1]; u.z=tl[bb][c4+2]; u.w=tl[bb][c4+3];
        if (vm && vm[(size_t)(bh>>4)*T_ + j0 + bb] == 0.f) { u.x=0;u.y=0;u.z=0;u.w=0; }
        *reinterpret_cast<ushort4*>(&d[(size_t)(j0+bb)*M + i0 + c4]) = u;
    }
}

// 8-wave cooperative-tile flash attention with in-block split-KV x2.
// Group g (waves 4g..4g+3) walks tiles [g*(qb+1), (g+1)*(qb+1)) for the SAME
// 128 q-rows; equal iteration counts keep the block barrier lockstep.
// Double-buffered LDS staging per group (global_load_lds w16, linear dest,
// pre-swizzled source — verbatim round 10). LDS-merge of the two groups'
// partials (round-5-proven algebra). qb mapping pairs heavy+light per CU.
__global__ __launch_bounds__(512, 2) void attn_fwd(
    const float* __restrict__ q, const float* __restrict__ fp,
    const float* __restrict__ hmask,
    const ushort* __restrict__ KT,   // bf16 [T][D] per bh (vmask'd rows zeroed)
    const ushort* __restrict__ VT,   // bf16 [D][T] per bh
    float* __restrict__ out)
{
    __shared__ __align__(16) ushort sbuf[2][2][8192];  // [grp][buf][K:0-4095|V:4096-8191]

    const int bid = blockIdx.x;
    const int bh = bid & (BH-1);
    const int idx = bid >> 5;                          // 0..15
    const int qb = (bid < 256) ? (15 - idx) : (idx - 8);  // CU pairs sum to 15
    const int tid = threadIdx.x;
    const int lane = tid & 63;
    const int wid8 = tid >> 6;                         // 0..7
    const int g = wid8 >> 2;                           // KV-split group
    const int w = wid8 & 3;                            // wave within group
    const int col = lane & 31;
    const int hi  = lane >> 5;
    const int i0w = qb*128 + w*32;                     // this wave's 32 q-rows

    const ushort* KTb = KT + (size_t)bh*T_*D_;
    const ushort* VTb = VT + (size_t)bh*T_*D_;

    const float hmv = hmask[(size_t)(bh>>4)*T_ + i0w + col];
    const float sscale = 1.4426950408889634f / fp[0];
    const float qs = (hmv != 0.f) ? sscale : 0.f;
    const float C1E10s = 1e-10f * 1.4426950408889634f;
    const float NINF = -__builtin_inff();

    // Q B-frags (pre-scaled): B[d = dc*16+hi*8+e][col]   (rounds 3-10 proven)
    const float* qp = q + (size_t)bh*T_*D_ + (size_t)(i0w+col)*D_ + hi*8;
    bf16x8 qf[4];
    #pragma unroll
    for (int dc=0; dc<4; ++dc){
        float4 x0 = *reinterpret_cast<const float4*>(qp + dc*16);
        float4 x1 = *reinterpret_cast<const float4*>(qp + dc*16 + 4);
        u32x4 dw;
        dw[0] = cvtpk(x0.x*qs, x0.y*qs);
        dw[1] = cvtpk(x0.z*qs, x0.w*qs);
        dw[2] = cvtpk(x1.x*qs, x1.y*qs);
        dw[3] = cvtpk(x1.z*qs, x1.w*qs);
        qf[dc] = __builtin_bit_cast(bf16x8, dw);
    }

    float m_run = NINF, l_run = 0.f;
    f32x16 o0, o1;
    #pragma unroll
    for (int r=0;r<16;++r){ o0[r]=0.f; o1[r]=0.f; }

    const unsigned uoff = (unsigned)(w*1024 + lane*16);  // staging byte cursor
    const unsigned swz = ((unsigned)(col&7)) << 4;       // frag-read swizzle

    // stage tile t into group buffer b (verbatim round-10 addressing)
    auto stage = [&](int b, int t){
        char* ldsK = (char*)&sbuf[g][b][0];
        char* ldsV = (char*)&sbuf[g][b][4096];
        const char* kbase = (const char*)KTb + (size_t)t*8192;
        #pragma unroll
        for (int i=0;i<2;++i){
            const unsigned u = i*4096u + uoff;
            const unsigned su = u ^ (((u>>7)&7u)<<4);
            __builtin_amdgcn_global_load_lds(
                (gbl_void*)(kbase + su),
                (lds_void*)(ldsK + i*4096 + w*1024), 16, 0, 0);
        }
        #pragma unroll
        for (int i=0;i<2;++i){
            const unsigned u = i*4096u + uoff;
            const unsigned dR = u>>7;
            const unsigned inr = (u&127u) ^ ((dR&7u)<<4);
            const char* src = (const char*)VTb + (size_t)dR*(T_*2) + (size_t)t*128 + inr;
            __builtin_amdgcn_global_load_lds(
                (gbl_void*)src,
                (lds_void*)(ldsV + i*4096 + w*1024), 16, 0, 0);
        }
    };

    const int n = qb + 1;          // iterations per group (equal for g=0,1)
    const int ts = g*n;            // group tile range [ts, ts+n)
    int bsel = 0;
    stage(0, ts);

    for (int it=0; it<n; ++it){
        const int t = ts + it, j0 = t*64;
        __syncthreads();           // drains prior stage (vmcnt 0) + barrier
        if (it+1 < n) stage(bsel^1, t+1);   // after barrier: clobber-safe

        if (j0 <= i0w + 31){
            // K frags from LDS (verbatim round 10)
            const char* sKb = (const char*)&sbuf[g][bsel][0];
            bf16x8 kf[8];
            #pragma unroll
            for (int kt=0;kt<2;++kt)
                #pragma unroll
                for (int dc=0;dc<4;++dc)
                    kf[kt*4+dc] = *reinterpret_cast<const bf16x8*>(
                        sKb + (((unsigned)(kt*4096 + dc*32 + col*128 + hi*16)) ^ swz));

            f32x16 s0, s1;
            #pragma unroll
            for (int r=0;r<16;++r){ s0[r]=0.f; s1[r]=0.f; }
            #pragma unroll
            for (int dc=0;dc<4;++dc){
                s0 = __builtin_amdgcn_mfma_f32_32x32x16_bf16(kf[dc],   qf[dc], s0, 0,0,0);
                s1 = __builtin_amdgcn_mfma_f32_32x32x16_bf16(kf[4+dc], qf[dc], s1, 0,0,0);
            }

            const char* sVb = (const char*)&sbuf[g][bsel][4096];
            bf16x8 vf[8];
            #pragma unroll
            for (int f=0;f<8;++f)
                vf[f] = *reinterpret_cast<const bf16x8*>(
                    sVb + (((unsigned)((f>>2)*4096 + (f&3)*32 + col*128 + hi*16)) ^ swz));

            // masking (rounds 3-10 proven)
            if (j0 + 63 <= i0w) {
                #pragma unroll
                for (int r=0;r<16;++r){
                    float x0v = s0[r]; s0[r] = (x0v==0.f) ? C1E10s : x0v;
                    float x1v = s1[r]; s1[r] = (x1v==0.f) ? C1E10s : x1v;
                }
            } else {
                const int th0 = i0w + col - j0 - 4*hi;
                const int th1 = th0 - 32;
                #pragma unroll
                for (int r=0;r<16;++r){
                    const int basr = (r&3) + 8*(r>>2);
                    float x0v = s0[r]; x0v = (x0v==0.f) ? C1E10s : x0v;
                    s0[r] = (basr <= th0) ? x0v : NINF;
                    float x1v = s1[r]; x1v = (x1v==0.f) ? C1E10s : x1v;
                    s1[r] = (basr <= th1) ? x1v : NINF;
                }
            }

            // online softmax (base-2), lane-local (rounds 3-10 proven)
            float mt = fmaxf(s0[0], s1[0]);
            #pragma unroll
            for (int r=1;r<16;++r) mt = fmaxf(mt, fmaxf(s0[r], s1[r]));
            mt = xhalf_max(mt);
            const float mn = fmaxf(m_run, mt);
            const float fac = __builtin_amdgcn_exp2f(m_run - mn);
            m_run = mn;
            float rs = 0.f;
            #pragma unroll
            for (int r=0;r<16;++r){
                float p0 = __builtin_amdgcn_exp2f(s0[r] - mn);
                float p1 = __builtin_amdgcn_exp2f(s1[r] - mn);
                s0[r]=p0; s1[r]=p1; rs += p0 + p1;
            }
            rs = xhalf_sum(rs);
            l_run = l_run*fac + rs;
            #pragma unroll
            for (int r=0;r<16;++r){ o0[r]*=fac; o1[r]*=fac; }

            // P -> bf16 B-frags (rounds 3-10 proven)
            bf16x8 pb[4];
            #pragma unroll
            for (int c2=0;c2<4;++c2){
                const f32x16& ps = (c2<2) ? s0 : s1;
                const int rb = (c2&1)*8;
                u32 a0 = cvtpk(ps[rb+0], ps[rb+1]);
                u32 a1 = cvtpk(ps[rb+2], ps[rb+3]);
                u32 a2 = cvtpk(ps[rb+4], ps[rb+5]);
                u32 a3 = cvtpk(ps[rb+6], ps[rb+7]);
                asm("v_permlane32_swap_b32 %0, %1" : "+v"(a0), "+v"(a2));
                asm("v_permlane32_swap_b32 %0, %1" : "+v"(a1), "+v"(a3));
                u32x4 dw; dw[0]=a0; dw[1]=a1; dw[2]=a2; dw[3]=a3;
                pb[c2] = __builtin_bit_cast(bf16x8, dw);
            }

            // O^T += V^T P^T
            #pragma unroll
            for (int c2=0;c2<4;++c2){
                o0 = __builtin_amdgcn_mfma_f32_32x32x16_bf16(vf[c2],   pb[c2], o0, 0,0,0);
                o1 = __builtin_amdgcn_mfma_f32_32x32x16_bf16(vf[4+c2], pb[c2], o1, 0,0,0);
            }
        }
        bsel ^= 1;
    }

    // ---- merge the two groups' partials (round-5 algebra, one partner) ----
    __syncthreads();                      // all staging/compute reads done
    float* F = (float*)&sbuf[0][0][0];
    float* sl = F + (size_t)(w*64 + lane)*36;   // 4*64*36*4B = 36.9KB <= 64KB
    if (g == 1){
        #pragma unroll
        for (int q4=0;q4<4;++q4){
            float4 a = {o0[4*q4], o0[4*q4+1], o0[4*q4+2], o0[4*q4+3]};
            *reinterpret_cast<float4*>(sl + 4*q4) = a;
            float4 b = {o1[4*q4], o1[4*q4+1], o1[4*q4+2], o1[4*q4+3]};
            *reinterpret_cast<float4*>(sl + 16 + 4*q4) = b;
        }
        sl[32] = m_run; sl[33] = l_run;
    }
    __syncthreads();
    if (g == 1) return;

    const float m1 = sl[32], l1 = sl[33];
    const float M = fmaxf(m_run, m1);     // m_run (g0) always finite
    const float e0 = __builtin_amdgcn_exp2f(m_run - M);
    const float e1 = __builtin_amdgcn_exp2f(m1 - M);
    const float L = l_run*e0 + l1*e1;
    #pragma unroll
    for (int q4=0;q4<4;++q4){
        float4 a = *reinterpret_cast<const float4*>(sl + 4*q4);
        o0[4*q4]   = o0[4*q4]*e0   + a.x*e1;
        o0[4*q4+1] = o0[4*q4+1]*e0 + a.y*e1;
        o0[4*q4+2] = o0[4*q4+2]*e0 + a.z*e1;
        o0[4*q4+3] = o0[4*q4+3]*e0 + a.w*e1;
        float4 b = *reinterpret_cast<const float4*>(sl + 16 + 4*q4);
        o1[4*q4]   = o1[4*q4]*e0   + b.x*e1;
        o1[4*q4+1] = o1[4*q4+1]*e0 + b.y*e1;
        o1[4*q4+2] = o1[4*q4+2]*e0 + b.z*e1;
        o1[4*q4+3] = o1[4*q4+3]*e0 + b.w*e1;
    }

    // epilogue: O = O^T / L, float4 stores (g0 waves cover all 128 rows)
    const float rinv = 1.0f / L;
    float* op = out + (size_t)bh*T_*D_ + (size_t)(i0w+col)*D_;
    #pragma unroll
    for (int q4=0;q4<4;++q4){
        float4 a = {o0[4*q4]*rinv, o0[4*q4+1]*rinv, o0[4*q4+2]*rinv, o0[4*q4+3]*rinv};
        *reinterpret_cast<float4*>(op + 8*q4 + 4*hi) = a;
        float4 b = {o1[4*q4]*rinv, o1[4*q4+1]*rinv, o1[4*q4+2]*rinv, o1[4*q4+3]*rinv};
        *reinterpret_cast<float4*>(op + 32 + 8*q4 + 4*hi) = b;
    }
}

extern "C" void kernel_launch(void* const* d_in, const int* in_sizes, int n_in,
                              void* d_out, int out_size, void* d_ws, size_t ws_size,
                              hipStream_t stream) {
    const float* q  = (const float*)d_in[0];
    const float* k  = (const float*)d_in[1];
    const float* v  = (const float*)d_in[2];
    const float* f  = (const float*)d_in[3];
    const float* vm = (const float*)d_in[4];
    const float* hm = (const float*)d_in[5];
    float* out = (float*)d_out;

    const size_t slab = (size_t)BH * T_ * D_;
    ushort* KT = (ushort*)d_ws;
    ushort* VT = KT + slab;

    // k: f32 [D][T] -> KT bf16 [T][D], vmask'd rows zeroed  (proven prep)
    hipLaunchKernelGGL(tr_bf16, dim3(BH, 1, T_/64), dim3(256), 0, stream,
                       k, KT, D_, T_, vm);
    // v: f32 [T][D] -> VT bf16 [D][T]
    hipLaunchKernelGGL(tr_bf16, dim3(BH, T_/64, 1), dim3(256), 0, stream,
                       v, VT, T_, D_, (const float*)nullptr);

    dim3 grid(512);    // 32 bh x 16 q-blocks; qb mapping balances CU pairs
    dim3 block(512);   // 8 waves: 2 KV-split groups x 4 q-waves
    hipLaunchKernelGGL(attn_fwd, grid, block, 0, stream, q, f, hm, KT, VT, out);
}

// Round 12
// 57.251 us; speedup vs baseline: 3.3423x; 1.1877x over previous
//
#include <hip/hip_runtime.h>
#include <hip/hip_bf16.h>

#define B_ 2
#define H_ 16
#define T_ 2048
#define D_ 64
#define BH (B_*H_)

typedef __attribute__((ext_vector_type(8))) short bf16x8;
typedef __attribute__((ext_vector_type(16))) float f32x16;
typedef __attribute__((ext_vector_type(4))) unsigned int u32x4;
typedef unsigned int u32;

typedef __attribute__((address_space(3))) void lds_void;
typedef __attribute__((address_space(1))) const void gbl_void;

__device__ __forceinline__ ushort f2bu(float x){
    __hip_bfloat16 h = __float2bfloat16(x);
    return __builtin_bit_cast(ushort, h);
}
__device__ __forceinline__ u32 cvtpk(float a, float b){
    u32 r; asm("v_cvt_pk_bf16_f32 %0, %1, %2" : "=v"(r) : "v"(a), "v"(b)); return r;
}
// Cross-half (lane ^ 32) reductions via permlane32_swap. Empty asm on b keeps
// it in its OWN register (round-4 lesson: coalescer self-swap bug -> NaN).
__device__ __forceinline__ float xhalf_max(float x){
    float a = x, b = x;
    asm("" : "+v"(b));
    asm("v_permlane32_swap_b32 %0, %1" : "+v"(a), "+v"(b));
    return fmaxf(a, b);
}
__device__ __forceinline__ float xhalf_sum(float x){
    float a = x, b = x;
    asm("" : "+v"(b));
    asm("v_permlane32_swap_b32 %0, %1" : "+v"(a), "+v"(b));
    return a + b;
}

// Fused prep (bodies verbatim from the rounds-2..11-proven tr_bf16):
//  blockIdx.y < 32: k f32 [D][T] -> KT bf16 [T][D], vmask'd key rows zeroed
//  blockIdx.y >= 32: v f32 [T][D] -> VT bf16 [D][T]
__global__ __launch_bounds__(256) void prep(
    const float* __restrict__ k, const float* __restrict__ v,
    const float* __restrict__ vm,
    ushort* __restrict__ KT, ushort* __restrict__ VT)
{
    __shared__ ushort tl[64][65];
    const int bh = blockIdx.x;
    const bool isK = (blockIdx.y < 32);
    const int ty = isK ? blockIdx.y : (blockIdx.y - 32);
    const int i0 = isK ? 0 : ty*64;
    const int j0 = isK ? ty*64 : 0;
    const int M = isK ? D_ : T_;
    const int N = isK ? T_ : D_;
    const float* s = (isK ? k : v) + (size_t)bh*M*N;
    ushort*      d = (isK ? KT : VT) + (size_t)bh*M*N;
    const int tid = threadIdx.x;
    const int rr = tid>>4, c4 = (tid&15)*4;
    #pragma unroll
    for (int p=0;p<4;++p){
        int a = p*16+rr;
        float4 x = *reinterpret_cast<const float4*>(&s[(size_t)(i0+a)*N + j0 + c4]);
        tl[c4+0][a]=f2bu(x.x); tl[c4+1][a]=f2bu(x.y);
        tl[c4+2][a]=f2bu(x.z); tl[c4+3][a]=f2bu(x.w);
    }
    __syncthreads();
    #pragma unroll
    for (int p=0;p<4;++p){
        int bb = p*16+rr;
        ushort4 u;
        u.x=tl[bb][c4]; u.y=tl[bb][c4+1]; u.z=tl[bb][c4+2]; u.w=tl[bb][c4+3];
        if (isK && vm[(size_t)(bh>>4)*T_ + j0 + bb] == 0.f) { u.x=0;u.y=0;u.z=0;u.w=0; }
        *reinterpret_cast<ushort4*>(&d[(size_t)(j0+bb)*M + i0 + c4]) = u;
    }
}

// Barrier-free flash attention: ONE wave per block, 32 q-rows, own
// double-buffered LDS (2 x 16KB). Wave stages its own 64-key tiles via
// global_load_lds (R10/R11-proven swizzled addressing), drains with a single
// vmcnt(0) per iteration (overlapped with compute). No s_barrier anywhere ->
// 5 blocks/CU of fully independent, phase-staggered waves.
__global__ __launch_bounds__(64, 2) void attn_fwd(
    const float* __restrict__ q, const float* __restrict__ fp,
    const float* __restrict__ hmask,
    const ushort* __restrict__ KT,   // bf16 [T][D] per bh (vmask'd rows zeroed)
    const ushort* __restrict__ VT,   // bf16 [D][T] per bh
    float* __restrict__ out)
{
    __shared__ __align__(16) ushort sbuf[2][8192];  // [buf][K:0-4095 | V:4096-8191]

    const int bid = blockIdx.x;
    const int bh = bid & (BH-1);
    const int qw = 63 - (bid >> 5);            // heavy-first, 32 rows per wave
    const int i0 = qw*32;
    const int lane = threadIdx.x & 63;
    const int col = lane & 31;
    const int hi  = lane >> 5;

    const ushort* KTb = KT + (size_t)bh*T_*D_;
    const ushort* VTb = VT + (size_t)bh*T_*D_;

    const float hmv = hmask[(size_t)(bh>>4)*T_ + i0 + col];
    const float sscale = 1.4426950408889634f / fp[0];
    const float qs = (hmv != 0.f) ? sscale : 0.f;   // hmask==0 -> row scores 0
    const float NINF = -__builtin_inff();

    // Q B-frags (pre-scaled): B[d = dc*16+hi*8+e][col]   (rounds 3-11 proven)
    const float* qp = q + (size_t)bh*T_*D_ + (size_t)(i0+col)*D_ + hi*8;
    bf16x8 qf[4];
    #pragma unroll
    for (int dc=0; dc<4; ++dc){
        float4 x0 = *reinterpret_cast<const float4*>(qp + dc*16);
        float4 x1 = *reinterpret_cast<const float4*>(qp + dc*16 + 4);
        u32x4 dw;
        dw[0] = cvtpk(x0.x*qs, x0.y*qs);
        dw[1] = cvtpk(x0.z*qs, x0.w*qs);
        dw[2] = cvtpk(x1.x*qs, x1.y*qs);
        dw[3] = cvtpk(x1.z*qs, x1.w*qs);
        qf[dc] = __builtin_bit_cast(bf16x8, dw);
    }

    float m_run = NINF, l_run = 0.f;
    f32x16 o0, o1;
    #pragma unroll
    for (int r=0;r<16;++r){ o0[r]=0.f; o1[r]=0.f; }

    const unsigned uoff = (unsigned)(lane*16);       // staging byte cursor
    const unsigned swz = ((unsigned)(col&7)) << 4;   // frag-read swizzle

    // stage tile t into buffer b (R10/R11-proven addressing, 16 x 1KB loads)
    auto stage = [&](int b, int t){
        char* ldsK = (char*)&sbuf[b][0];
        char* ldsV = (char*)&sbuf[b][4096];
        const char* kbase = (const char*)KTb + (size_t)t*8192;
        #pragma unroll
        for (int i=0;i<8;++i){
            const unsigned u = i*1024u + uoff;
            const unsigned su = u ^ (((u>>7)&7u)<<4);
            __builtin_amdgcn_global_load_lds(
                (gbl_void*)(kbase + su),
                (lds_void*)(ldsK + i*1024), 16, 0, 0);
        }
        #pragma unroll
        for (int i=0;i<8;++i){
            const unsigned u = i*1024u + uoff;
            const unsigned dR = u>>7;
            const unsigned inr = (u&127u) ^ ((dR&7u)<<4);
            const char* src = (const char*)VTb + (size_t)dR*(T_*2) + (size_t)t*128 + inr;
            __builtin_amdgcn_global_load_lds(
                (gbl_void*)src,
                (lds_void*)(ldsV + i*1024), 16, 0, 0);
        }
    };

    const int n = (qw >> 1) + 1;     // tiles 0..n-1 cover keys <= i0+31
    int buf = 0;
    stage(0, 0);
    asm volatile("s_waitcnt vmcnt(0)" ::: "memory");

    for (int t=0; t<n; ++t){
        const int j0 = t*64;
        if (t+1 < n) stage(buf^1, t+1);   // prefetch; drains at loop bottom

        // K frags from LDS (verbatim R10/R11)
        const char* sKb = (const char*)&sbuf[buf][0];
        bf16x8 kf[8];
        #pragma unroll
        for (int kt=0;kt<2;++kt)
            #pragma unroll
            for (int dc=0;dc<4;++dc)
                kf[kt*4+dc] = *reinterpret_cast<const bf16x8*>(
                    sKb + (((unsigned)(kt*4096 + dc*32 + col*128 + hi*16)) ^ swz));

        f32x16 s0, s1;
        #pragma unroll
        for (int r=0;r<16;++r){ s0[r]=0.f; s1[r]=0.f; }
        #pragma unroll
        for (int dc=0;dc<4;++dc){
            s0 = __builtin_amdgcn_mfma_f32_32x32x16_bf16(kf[dc],   qf[dc], s0, 0,0,0);
            s1 = __builtin_amdgcn_mfma_f32_32x32x16_bf16(kf[4+dc], qf[dc], s1, 0,0,0);
        }

        // V frags (issued before softmax; latency hides under it)
        const char* sVb = (const char*)&sbuf[buf][4096];
        bf16x8 vf[8];
        #pragma unroll
        for (int f=0;f<8;++f)
            vf[f] = *reinterpret_cast<const bf16x8*>(
                sVb + (((unsigned)((f>>2)*4096 + (f&3)*32 + col*128 + hi*16)) ^ swz));

        // causal -inf only on the (single) diagonal tile. NOTE: the reference's
        // masked_fill(s==0, 1e-10) is a numeric no-op (exp(1e-10-m) == exp(0-m)
        // in fp32); masked scores are exactly 0 via zeroed K rows / zeroed Q.
        if (j0 + 63 > i0) {
            const int th0 = i0 + col - j0 - 4*hi;
            const int th1 = th0 - 32;
            #pragma unroll
            for (int r=0;r<16;++r){
                const int basr = (r&3) + 8*(r>>2);
                s0[r] = (basr <= th0) ? s0[r] : NINF;
                s1[r] = (basr <= th1) ? s1[r] : NINF;
            }
        }

        // per-row (lane-local) max, tree + cross-half
        float tm[8];
        #pragma unroll
        for (int i=0;i<8;++i)
            tm[i] = fmaxf(fmaxf(s0[2*i], s0[2*i+1]), fmaxf(s1[2*i], s1[2*i+1]));
        #pragma unroll
        for (int st=4; st>=1; st>>=1)
            #pragma unroll
            for (int i=0;i<st;++i) tm[i] = fmaxf(tm[i], tm[i+st]);
        const float mt = xhalf_max(tm[0]);

        // defer-max (T13): rescale only when some row's max grew past THR=8
        if (__any(!(mt <= m_run + 8.0f))) {
            const float mn = fmaxf(m_run, mt);
            const float fac = __builtin_amdgcn_exp2f(m_run - mn);
            m_run = mn;
            l_run *= fac;
            #pragma unroll
            for (int r=0;r<16;++r){ o0[r]*=fac; o1[r]*=fac; }
        }

        // P = exp2(s - m_run), row-sum via tree + cross-half
        float tsum[8];
        #pragma unroll
        for (int i=0;i<8;++i){
            float p00 = __builtin_amdgcn_exp2f(s0[2*i]   - m_run);
            float p01 = __builtin_amdgcn_exp2f(s0[2*i+1] - m_run);
            float p10 = __builtin_amdgcn_exp2f(s1[2*i]   - m_run);
            float p11 = __builtin_amdgcn_exp2f(s1[2*i+1] - m_run);
            s0[2*i]=p00; s0[2*i+1]=p01; s1[2*i]=p10; s1[2*i+1]=p11;
            tsum[i] = (p00+p01) + (p10+p11);
        }
        #pragma unroll
        for (int st=4; st>=1; st>>=1)
            #pragma unroll
            for (int i=0;i<st;++i) tsum[i] += tsum[i+st];
        l_run += xhalf_sum(tsum[0]);

        // P -> bf16 B-frags (rounds 3-11 proven)
        bf16x8 pb[4];
        #pragma unroll
        for (int c2=0;c2<4;++c2){
            const f32x16& ps = (c2<2) ? s0 : s1;
            const int rb = (c2&1)*8;
            u32 a0 = cvtpk(ps[rb+0], ps[rb+1]);
            u32 a1 = cvtpk(ps[rb+2], ps[rb+3]);
            u32 a2 = cvtpk(ps[rb+4], ps[rb+5]);
            u32 a3 = cvtpk(ps[rb+6], ps[rb+7]);
            asm("v_permlane32_swap_b32 %0, %1" : "+v"(a0), "+v"(a2));
            asm("v_permlane32_swap_b32 %0, %1" : "+v"(a1), "+v"(a3));
            u32x4 dw; dw[0]=a0; dw[1]=a1; dw[2]=a2; dw[3]=a3;
            pb[c2] = __builtin_bit_cast(bf16x8, dw);
        }

        // O^T += V^T P^T
        #pragma unroll
        for (int c2=0;c2<4;++c2){
            o0 = __builtin_amdgcn_mfma_f32_32x32x16_bf16(vf[c2],   pb[c2], o0, 0,0,0);
            o1 = __builtin_amdgcn_mfma_f32_32x32x16_bf16(vf[4+c2], pb[c2], o1, 0,0,0);
        }

        asm volatile("s_waitcnt vmcnt(0)" ::: "memory");  // next tile landed
        buf ^= 1;
    }

    // epilogue: O = O^T / l, float4 stores (rounds 10-11 proven)
    const float rinv = 1.0f / l_run;
    float* op = out + (size_t)bh*T_*D_ + (size_t)(i0+col)*D_;
    #pragma unroll
    for (int q4=0;q4<4;++q4){
        float4 a = {o0[4*q4]*rinv, o0[4*q4+1]*rinv, o0[4*q4+2]*rinv, o0[4*q4+3]*rinv};
        *reinterpret_cast<float4*>(op + 8*q4 + 4*hi) = a;
        float4 b = {o1[4*q4]*rinv, o1[4*q4+1]*rinv, o1[4*q4+2]*rinv, o1[4*q4+3]*rinv};
        *reinterpret_cast<float4*>(op + 32 + 8*q4 + 4*hi) = b;
    }
}

extern "C" void kernel_launch(void* const* d_in, const int* in_sizes, int n_in,
                              void* d_out, int out_size, void* d_ws, size_t ws_size,
                              hipStream_t stream) {
    const float* q  = (const float*)d_in[0];
    const float* k  = (const float*)d_in[1];
    const float* v  = (const float*)d_in[2];
    const float* f  = (const float*)d_in[3];
    const float* vm = (const float*)d_in[4];
    const float* hm = (const float*)d_in[5];
    float* out = (float*)d_out;

    const size_t slab = (size_t)BH * T_ * D_;
    ushort* KT = (ushort*)d_ws;
    ushort* VT = KT + slab;

    // fused K+V prep (proven bodies, one launch)
    hipLaunchKernelGGL(prep, dim3(BH, 64), dim3(256), 0, stream, k, v, vm, KT, VT);

    dim3 grid(2048);   // 32 bh x 64 q-waves, heavy-first; 1 wave per block
    dim3 block(64);
    hipLaunchKernelGGL(attn_fwd, grid, block, 0, stream, q, f, hm, KT, VT, out);
}